// Round 4
// baseline (1531.589 us; speedup 1.0000x reference)
//
#include <hip/hip_runtime.h>
#include <math.h>

// GAT layer w/ edge features.
// Edge GEMM [E,128]@[128,160] in bf16 MFMA (cols 0..127 = Wec, 128..135 = Ae attn, rest 0).
// Node path stays f32. CSR segment softmax, unroll-4 aggregation.

constexpr int NN = 50000;
constexpr int NE = 600000;
constexpr int APAD = 132;   // f32 node-GEMM A stride
constexpr int BSTR = 160;   // f32 node-GEMM B stride (16 groups * 10)

typedef __attribute__((ext_vector_type(8))) short bf16x8;
typedef __attribute__((ext_vector_type(4))) float f32x4;

__device__ __forceinline__ unsigned short f2bf(float f) {
    unsigned u = __float_as_uint(f);
    u += 0x7fffu + ((u >> 16) & 1u);   // RNE
    return (unsigned short)(u >> 16);
}

// ---------------- weight combine ----------------
// Bcomb (bf16, swizzled, [160 cols][128 k] "row"-major 256B/col):
//   cols 0..127 : WecT[c][i] = sum_k We[h][i][k]*Wproj[h][k][o]  (c=h*16+o)
//   cols 128..135: Ae[i][h]  = sum_k We[h][i][k]*Wattn[h][k]
//   cols 136..159: 0
// byte offset for (col, kdim i): col*256 + ((i>>3)^(col&15))*16 + (i&7)*2
// Wn (f32): node GEMM B, Wn[i][c] = Wh[h][i][o]
__global__ void k_combine(const float* __restrict__ Wh, const float* __restrict__ We,
                          const float* __restrict__ Wproj, const float* __restrict__ Wattn,
                          unsigned char* __restrict__ Bcomb, float* __restrict__ Wn)
{
    int tid = blockIdx.x * 256 + threadIdx.x;
    if (tid < 16384) {
        int i = tid >> 7, c = tid & 127;
        int h = c >> 4, o = c & 15;
        float s = 0.f;
#pragma unroll
        for (int k = 0; k < 16; ++k)
            s += We[h*2048 + i*16 + k] * Wproj[h*768 + k*16 + o];
        int off = c*256 + (((i>>3) ^ (c&15))<<4) + (i&7)*2;
        *(unsigned short*)(Bcomb + off) = f2bf(s);
    } else if (tid < 17408) {
        int q = tid - 16384;
        int i = q >> 3, h = q & 7;
        float s = 0.f;
#pragma unroll
        for (int k = 0; k < 16; ++k)
            s += We[h*2048 + i*16 + k] * Wattn[h*48 + k];
        int col = 128 + h;
        int off = col*256 + (((i>>3) ^ (col&15))<<4) + (i&7)*2;
        *(unsigned short*)(Bcomb + off) = f2bf(s);
    } else if (tid < 33792) {
        int q = tid - 17408;
        int i = q >> 7, c = q & 127;
        int h = c >> 4, o = c & 15;
        Wn[i*128 + c] = Wh[h*2048 + i*16 + o];
    } else if (tid < 36864) {
        int q = tid - 33792;          // 24 cols * 128 k
        int col = 136 + (q >> 7), i = q & 127;
        int off = col*256 + (((i>>3) ^ (col&15))<<4) + (i&7)*2;
        *(unsigned short*)(Bcomb + off) = 0;
    }
}

// ---------------- f32 GEMM helpers (node GEMM only) ----------------
__device__ __forceinline__ void stage_ab(const float* __restrict__ Aglob,
                                         const float* __restrict__ Bglob,
                                         float* Al, float* Bl, int m0, int M)
{
    int t = threadIdx.x;
    {
        int r = t >> 2, kc = t & 3;
        int gr = m0 + r; if (gr >= M) gr = M - 1;
        const float4* s4 = (const float4*)(Aglob + (size_t)gr*128 + kc*32);
        float4* d4 = (float4*)(Al + r*APAD + kc*32);
#pragma unroll
        for (int i = 0; i < 8; ++i) d4[i] = s4[i];
    }
    {
        const float2* B2 = (const float2*)Bglob;
#pragma unroll
        for (int it = 0; it < 16; ++it) {
            int q = it*512 + t;
            int k = q >> 6, c2 = q & 63;
            int c = c2*2, g = c >> 3, j = c & 7;
            float2 v = B2[q];
            Bl[k*BSTR + g*10 + j]     = v.x;
            Bl[k*BSTR + g*10 + j + 1] = v.y;
        }
    }
}

__device__ __forceinline__ void mm_core(const float* Al, const float* Bl, float acc[4][8])
{
    int t = threadIdx.x;
    int rowg = t >> 4, colg = t & 15;
    int r0 = rowg * 4;
#pragma unroll
    for (int i = 0; i < 4; ++i)
#pragma unroll
        for (int j = 0; j < 8; ++j) acc[i][j] = 0.f;
#pragma unroll 4
    for (int k = 0; k < 128; ++k) {
        float a0 = Al[(r0+0)*APAD + k];
        float a1 = Al[(r0+1)*APAD + k];
        float a2 = Al[(r0+2)*APAD + k];
        float a3 = Al[(r0+3)*APAD + k];
        const float* bp = Bl + k*BSTR + colg*10;
#pragma unroll
        for (int j = 0; j < 8; ++j) {
            float b = bp[j];
            acc[0][j] += a0 * b;
            acc[1][j] += a1 * b;
            acc[2][j] += a2 * b;
            acc[3][j] += a3 * b;
        }
    }
}

// ---------------- node GEMM: z_h = h @ Wn (f32) ----------------
__global__ __launch_bounds__(512, 2) void k_node_gemm(const float* __restrict__ hg,
                                                      const float* __restrict__ Wn,
                                                      float* __restrict__ z_h)
{
    __shared__ float Al[128*APAD];
    __shared__ float Bl[128*BSTR];
    int m0 = blockIdx.x * 128;
    stage_ab(hg, Wn, Al, Bl, m0, NN);
    __syncthreads();
    float acc[4][8];
    mm_core(Al, Bl, acc);
    int t = threadIdx.x;
    int rowg = t >> 4, colg = t & 15, r0 = rowg*4;
#pragma unroll
    for (int i = 0; i < 4; ++i) {
        int gr = m0 + r0 + i;
        if (gr < NN) {
            float4* dp = (float4*)(z_h + (size_t)gr*128 + colg*8);
            dp[0] = make_float4(acc[i][0], acc[i][1], acc[i][2], acc[i][3]);
            dp[1] = make_float4(acc[i][4], acc[i][5], acc[i][6], acc[i][7]);
        }
    }
}

// ---------------- node post: p_s/p_d/a_s/a_d from z_h ----------------
__global__ __launch_bounds__(256) void k_nodepost(const float* __restrict__ z_h,
    const float* __restrict__ Wproj, const float* __restrict__ Wattn,
    float* __restrict__ p_s, float* __restrict__ p_d,
    float* __restrict__ a_s, float* __restrict__ a_d)
{
    __shared__ float Wps[16*128], Wpd[16*128], Was[128], Wad[128];
    __shared__ float z2[2*140];
    int t = threadIdx.x;
    for (int q = t; q < 2048; q += 256) {
        int k = q >> 7, rest = q & 127, h = rest >> 4, o = rest & 15;
        Wps[q] = Wproj[h*768 + (16+k)*16 + o];
        Wpd[q] = Wproj[h*768 + (32+k)*16 + o];
    }
    if (t < 128) {
        int h = t >> 4, k = t & 15;
        Was[t] = Wattn[h*48 + 16 + k];
        Wad[t] = Wattn[h*48 + 32 + k];
    }
    int nh = t >> 7, rest = t & 127, hh = rest >> 4, oo = rest & 15;
    int n0 = blockIdx.x * 32;
    for (int it = 0; it < 16; ++it) {
        int n = n0 + it*2 + nh;
        __syncthreads();
        {
            float v = 0.f;
            if (n < NN) v = z_h[(size_t)n*128 + hh*16 + oo];
            z2[nh*140 + hh*17 + oo] = v;
        }
        __syncthreads();
        if (n < NN) {
            const float* zz = z2 + nh*140 + hh*17;
            float ps = 0.f, pd = 0.f, as_ = 0.f, ad_ = 0.f;
#pragma unroll
            for (int k = 0; k < 16; ++k) {
                float zv = zz[k];
                ps  += zv * Wps[k*128 + hh*16 + oo];
                pd  += zv * Wpd[k*128 + hh*16 + oo];
                as_ += zv * Was[hh*16 + k];
                ad_ += zv * Wad[hh*16 + k];
            }
            p_s[(size_t)n*128 + rest] = ps;
            p_d[(size_t)n*128 + rest] = pd;
            if (oo == 0) { a_s[n*8 + hh] = as_; a_d[n*8 + hh] = ad_; }
        }
    }
}

// ---------------- edge GEMM (bf16 MFMA) + attn + e_out ----------------
// 256 threads = 4 waves, tile 128 rows x 160 cols, K=128 single shot.
// Wave grid 2Mx2N: wave tile 64x80 (M_rep=4, N_rep=5), mfma_f32_16x16x32_bf16.
// LDS: A bf16 swizzled 32KB + Bt bf16 swizzled 40KB, reused as C f32 [128][132].
union EdgeSM {
    struct { __align__(16) unsigned char A[32768]; __align__(16) unsigned char Bt[40960]; } s;
    float C[128*132];
};

__global__ __launch_bounds__(256) void k_edge(const float* __restrict__ eg,
    const unsigned char* __restrict__ Bcomb, const float* __restrict__ bproj,
    const int* __restrict__ src, const int* __restrict__ dst,
    const float* __restrict__ p_s, const float* __restrict__ p_d,
    const float* __restrict__ a_s, const float* __restrict__ a_d,
    float* __restrict__ attn, float* __restrict__ e_out)
{
    __shared__ EdgeSM sm;
    __shared__ float bpl[128];
    const int t = threadIdx.x;
    const int m0 = blockIdx.x * 128;

    // ---- stage A: f32 -> bf16, chunk-swizzled (chunk ^= row&15) ----
#pragma unroll
    for (int it = 0; it < 16; ++it) {
        int q = it*256 + t;                 // float4 id, 4096 total
        int row = q >> 5, c4 = q & 31;
        int gr = m0 + row; if (gr >= NE) gr = NE - 1;
        float4 v = *(const float4*)(eg + (size_t)gr*128 + c4*4);
        unsigned u0 = (unsigned)f2bf(v.x) | ((unsigned)f2bf(v.y) << 16);
        unsigned u1 = (unsigned)f2bf(v.z) | ((unsigned)f2bf(v.w) << 16);
        int off = row*256 + (((c4>>1) ^ (row&15))<<4) + (c4&1)*8;
        *(uint2*)(sm.s.A + off) = make_uint2(u0, u1);
    }
    // ---- stage Bt: already bf16+swizzled in global, linear copy 40KB ----
    {
        const uint4* bsrc = (const uint4*)Bcomb;
        uint4* bdst = (uint4*)sm.s.Bt;
#pragma unroll
        for (int it = 0; it < 10; ++it) {
            int q = it*256 + t;
            bdst[q] = bsrc[q];
        }
    }
    if (t < 128) bpl[t] = bproj[t];
    __syncthreads();

    // ---- MFMA K-loop ----
    const int w = t >> 6, l = t & 63;
    const int lc = l & 15, lk = l >> 4;
    const int wm0 = (w >> 1) * 64, wn0 = (w & 1) * 80;
    f32x4 acc[4][5];
#pragma unroll
    for (int m = 0; m < 4; ++m)
#pragma unroll
        for (int n = 0; n < 5; ++n) acc[m][n] = (f32x4){0.f, 0.f, 0.f, 0.f};

#pragma unroll
    for (int ks = 0; ks < 4; ++ks) {
        const int swz = ((ks*4 + lk) ^ lc) << 4;
        bf16x8 af[4], bfr[5];
#pragma unroll
        for (int m = 0; m < 4; ++m) {
            int row = wm0 + m*16 + lc;
            af[m] = *(const bf16x8*)(sm.s.A + row*256 + swz);
        }
#pragma unroll
        for (int n = 0; n < 5; ++n) {
            int col = wn0 + n*16 + lc;
            bfr[n] = *(const bf16x8*)(sm.s.Bt + col*256 + swz);
        }
#pragma unroll
        for (int m = 0; m < 4; ++m)
#pragma unroll
            for (int n = 0; n < 5; ++n)
                acc[m][n] = __builtin_amdgcn_mfma_f32_16x16x32_bf16(af[m], bfr[n], acc[m][n], 0, 0, 0);
    }

    // ---- attn epilogue: cols 128..135 live in odd waves, frag n=3 ----
    if (w & 1) {
#pragma unroll
        for (int m = 0; m < 4; ++m) {
            int rbase = m0 + wm0 + m*16 + lk*4;
#pragma unroll
            for (int i = 0; i < 4; ++i) {
                int er = rbase + i;
                if (er < NE && lc < 8) {
                    float v = acc[m][3][i];
                    int sj = src[er], dj = dst[er];
                    v += a_s[sj*8 + lc] + a_d[dj*8 + lc];
                    v = v > 0.f ? v : 0.01f * v;
                    attn[(size_t)er*8 + lc] = v;
                }
            }
        }
    }
    __syncthreads();   // all LDS frag reads done -> safe to overwrite as C

    // ---- bounce acc (cols < 128) into LDS C[128][132] ----
    {
        const int nlim = (w & 1) ? 3 : 5;
#pragma unroll
        for (int m = 0; m < 4; ++m)
#pragma unroll 5
            for (int n = 0; n < 5; ++n) {
                if (n < nlim) {
                    int col = wn0 + n*16 + lc;
                    int rbase = wm0 + m*16 + lk*4;
#pragma unroll
                    for (int i = 0; i < 4; ++i)
                        sm.C[(rbase + i)*132 + col] = acc[m][n][i];
                }
            }
    }
    __syncthreads();

    // ---- gather epilogue: e_out = e + elu(C + p_s[src] + p_d[dst] + bproj) ----
    {
        int r = t >> 1, cs = (t & 1) * 64;
        int er = m0 + r;
        if (er < NE) {
            int sj = src[er], dj = dst[er];
            const float4* psp = (const float4*)(p_s + (size_t)sj*128 + cs);
            const float4* pdp = (const float4*)(p_d + (size_t)dj*128 + cs);
            const float4* evp = (const float4*)(eg + (size_t)er*128 + cs);
            float4* op = (float4*)(e_out + (size_t)er*128 + cs);
#pragma unroll
            for (int j = 0; j < 16; ++j) {
                int c = cs + j*4;
                float4 cv = *(const float4*)&sm.C[r*132 + c];
                float4 ps = psp[j], pd = pdp[j], ev = evp[j];
                float o0 = cv.x + ps.x + pd.x + bpl[c+0];
                float o1 = cv.y + ps.y + pd.y + bpl[c+1];
                float o2 = cv.z + ps.z + pd.z + bpl[c+2];
                float o3 = cv.w + ps.w + pd.w + bpl[c+3];
                o0 = o0 > 0.f ? o0 : expm1f(o0);
                o1 = o1 > 0.f ? o1 : expm1f(o1);
                o2 = o2 > 0.f ? o2 : expm1f(o2);
                o3 = o3 > 0.f ? o3 : expm1f(o3);
                op[j] = make_float4(ev.x + o0, ev.y + o1, ev.z + o2, ev.w + o3);
            }
        }
    }
}

// ---------------- CSR build ----------------
__global__ void k_hist(const int* __restrict__ dst, int* __restrict__ deg)
{
    int e = blockIdx.x*256 + threadIdx.x;
    if (e < NE) atomicAdd(&deg[dst[e]], 1);
}

__global__ __launch_bounds__(1024) void k_scan1(const int* __restrict__ deg,
                                                int* __restrict__ offs, int* __restrict__ bsum)
{
    __shared__ int s[1024];
    int t = threadIdx.x;
    int idx = blockIdx.x*1024 + t;
    int v = (idx < NN) ? deg[idx] : 0;
    s[t] = v;
    __syncthreads();
    for (int off = 1; off < 1024; off <<= 1) {
        int x = (t >= off) ? s[t - off] : 0;
        __syncthreads();
        s[t] += x;
        __syncthreads();
    }
    if (idx < NN) offs[idx] = s[t] - v;
    if (t == 1023) bsum[blockIdx.x] = s[1023];
}

__global__ void k_scan2(const int* __restrict__ bsum, int* __restrict__ bases)
{
    int i = threadIdx.x;
    int v = (i < 49) ? bsum[i] : 0;
    int incl = v;
#pragma unroll
    for (int off = 1; off < 64; off <<= 1) {
        int x = __shfl_up(incl, off, 64);
        if (i >= off) incl += x;
    }
    if (i < 49) bases[i] = incl - v;
}

__global__ void k_scan3(int* __restrict__ offs, const int* __restrict__ bases,
                        int* __restrict__ cursor)
{
    int n = blockIdx.x*256 + threadIdx.x;
    if (n < NN) {
        int v = offs[n] + bases[n >> 10];
        offs[n] = v;
        cursor[n] = v;
    }
}

__global__ void k_scatter(const int* __restrict__ dst, int* __restrict__ cursor,
                          int* __restrict__ eids)
{
    int e = blockIdx.x*256 + threadIdx.x;
    if (e < NE) {
        int p = atomicAdd(&cursor[dst[e]], 1);
        eids[p] = e;
    }
}

// ---------------- per-node segment softmax + aggregate ----------------
// 256 threads = 2 nodes; unroll-4 independent accumulator chains.
__global__ __launch_bounds__(256) void k_agg(const float* __restrict__ hg,
    const float* __restrict__ z_h, const float* __restrict__ attn,
    const int* __restrict__ eids, const int* __restrict__ offs, const int* __restrict__ deg,
    const int* __restrict__ src, float* __restrict__ h_out)
{
    int half = threadIdx.x >> 7;
    int t = threadIdx.x & 127;
    int n = blockIdx.x * 2 + half;
    int hh = t >> 4;
    int dg = deg[n];
    int o0 = offs[n];
    float m = -INFINITY;
    for (int j = (t & 15); j < dg; j += 16) {
        int e = eids[o0 + j];
        m = fmaxf(m, attn[(size_t)e*8 + hh]);
    }
#pragma unroll
    for (int s = 1; s < 16; s <<= 1) m = fmaxf(m, __shfl_xor(m, s, 64));

    float n0 = 0.f, n1 = 0.f, n2 = 0.f, n3 = 0.f;
    float d0 = 0.f, d1 = 0.f, d2 = 0.f, d3 = 0.f;
    int j = 0;
    for (; j + 4 <= dg; j += 4) {
        int e0 = eids[o0 + j + 0];
        int e1 = eids[o0 + j + 1];
        int e2 = eids[o0 + j + 2];
        int e3 = eids[o0 + j + 3];
        int s0 = src[e0], s1 = src[e1], s2 = src[e2], s3 = src[e3];
        float x0 = expf(attn[(size_t)e0*8 + hh] - m);
        float x1 = expf(attn[(size_t)e1*8 + hh] - m);
        float x2 = expf(attn[(size_t)e2*8 + hh] - m);
        float x3 = expf(attn[(size_t)e3*8 + hh] - m);
        d0 += x0; d1 += x1; d2 += x2; d3 += x3;
        n0 += x0 * z_h[(size_t)s0*128 + t];
        n1 += x1 * z_h[(size_t)s1*128 + t];
        n2 += x2 * z_h[(size_t)s2*128 + t];
        n3 += x3 * z_h[(size_t)s3*128 + t];
    }
    for (; j < dg; ++j) {
        int e = eids[o0 + j];
        float x = expf(attn[(size_t)e*8 + hh] - m);
        d0 += x;
        n0 += x * z_h[(size_t)src[e]*128 + t];
    }
    float num = (n0 + n1) + (n2 + n3);
    float den = (d0 + d1) + (d2 + d3);
    float hag = num / fmaxf(den, 1e-9f);
    float el = hag > 0.f ? hag : expm1f(hag);
    h_out[(size_t)n*128 + t] = hg[(size_t)n*128 + t] + el;
}

// ---------------- launcher ----------------
extern "C" void kernel_launch(void* const* d_in, const int* in_sizes, int n_in,
                              void* d_out, int out_size, void* d_ws, size_t ws_size,
                              hipStream_t stream)
{
    const float* h     = (const float*)d_in[0];
    const float* e     = (const float*)d_in[1];
    const int*   src   = (const int*)d_in[2];
    const int*   dst   = (const int*)d_in[3];
    const float* Wh    = (const float*)d_in[4];
    const float* We    = (const float*)d_in[5];
    const float* Wproj = (const float*)d_in[6];
    const float* bproj = (const float*)d_in[7];
    const float* Wattn = (const float*)d_in[8];
    float* h_out = (float*)d_out;
    float* e_out = h_out + (size_t)NN * 128;

    char* w = (char*)d_ws;
    auto alloc = [&](size_t bytes) {
        char* p = w;
        w += (bytes + 255) & ~(size_t)255;
        return p;
    };
    unsigned char* Bcomb = (unsigned char*)alloc(160 * 256);     // bf16 swizzled B
    float* Wn   = (float*)alloc(16384 * 4);
    float* z_h  = (float*)alloc((size_t)NN * 128 * 4);
    float* p_s  = (float*)alloc((size_t)NN * 128 * 4);
    float* p_d  = (float*)alloc((size_t)NN * 128 * 4);
    float* a_s  = (float*)alloc((size_t)NN * 8 * 4);
    float* a_d  = (float*)alloc((size_t)NN * 8 * 4);
    float* attn = (float*)alloc((size_t)NE * 8 * 4);
    int* deg    = (int*)alloc((size_t)NN * 4);
    int* offs   = (int*)alloc((size_t)NN * 4);
    int* cursor = (int*)alloc((size_t)NN * 4);
    int* eids   = (int*)alloc((size_t)NE * 4);
    int* bsum   = (int*)alloc(64 * 4);
    int* bases  = (int*)alloc(64 * 4);

    hipMemsetAsync(deg, 0, (size_t)NN * 4, stream);

    k_combine<<<144, 256, 0, stream>>>(Wh, We, Wproj, Wattn, Bcomb, Wn);
    k_node_gemm<<<(NN + 127) / 128, 512, 0, stream>>>(h, Wn, z_h);
    k_nodepost<<<(NN + 31) / 32, 256, 0, stream>>>(z_h, Wproj, Wattn, p_s, p_d, a_s, a_d);
    k_edge<<<(NE + 127) / 128, 256, 0, stream>>>(e, Bcomb, bproj, src, dst,
                                                 p_s, p_d, a_s, a_d, attn, e_out);
    k_hist<<<(NE + 255) / 256, 256, 0, stream>>>(dst, deg);
    k_scan1<<<49, 1024, 0, stream>>>(deg, offs, bsum);
    k_scan2<<<1, 64, 0, stream>>>(bsum, bases);
    k_scan3<<<(NN + 255) / 256, 256, 0, stream>>>(offs, bases, cursor);
    k_scatter<<<(NE + 255) / 256, 256, 0, stream>>>(dst, cursor, eids);
    k_agg<<<NN / 2, 256, 0, stream>>>(h, z_h, attn, eids, offs, deg, src, h_out);
}

// Round 6
// 908.425 us; speedup vs baseline: 1.6860x; 1.6860x over previous
//
#include <hip/hip_runtime.h>
#include <math.h>

// GAT layer w/ edge features.
// Edge GEMM [E,128]@[128,160] bf16 MFMA (cols 0..127 = Wec, 128..135 = Ae attn).
// Epilogues use full-row (16-lane/row) geometry: every global ld/st instruction
// covers whole 64B sectors (round-4 partial-sector writes caused 2.2GB FETCH).
// p_s/p_d and k_agg's z_h copy are bf16 to halve gather traffic.

constexpr int NN = 50000;
constexpr int NE = 600000;
constexpr int APAD = 132;   // f32 node-GEMM A stride
constexpr int BSTR = 160;   // f32 node-GEMM B stride (16 groups * 10)
constexpr int CSTR = 140;   // k_edge LDS C stride (cols 0..135 used)

typedef __attribute__((ext_vector_type(8))) short bf16x8;
typedef __attribute__((ext_vector_type(8))) unsigned short u16x8;
typedef __attribute__((ext_vector_type(4))) float f32x4;

__device__ __forceinline__ unsigned short f2bf(float f) {
    unsigned u = __float_as_uint(f);
    u += 0x7fffu + ((u >> 16) & 1u);   // RNE
    return (unsigned short)(u >> 16);
}
__device__ __forceinline__ float bf2f(unsigned short us) {
    return __uint_as_float((unsigned)us << 16);
}

// ---------------- weight combine ----------------
// Bcomb (bf16, swizzled, [160 cols][128 k], 256B/col):
//   cols 0..127 : WecT[c][i] = sum_k We[h][i][k]*Wproj[h][k][o]  (c=h*16+o)
//   cols 128..135: Ae[i][h]  = sum_k We[h][i][k]*Wattn[h][k]
//   cols 136..159: 0
// byte offset for (col, k-dim i): col*256 + ((i>>3)^(col&15))*16 + (i&7)*2
__global__ void k_combine(const float* __restrict__ Wh, const float* __restrict__ We,
                          const float* __restrict__ Wproj, const float* __restrict__ Wattn,
                          unsigned char* __restrict__ Bcomb, float* __restrict__ Wn)
{
    int tid = blockIdx.x * 256 + threadIdx.x;
    if (tid < 16384) {
        int i = tid >> 7, c = tid & 127;
        int h = c >> 4, o = c & 15;
        float s = 0.f;
#pragma unroll
        for (int k = 0; k < 16; ++k)
            s += We[h*2048 + i*16 + k] * Wproj[h*768 + k*16 + o];
        int off = c*256 + (((i>>3) ^ (c&15))<<4) + (i&7)*2;
        *(unsigned short*)(Bcomb + off) = f2bf(s);
    } else if (tid < 17408) {
        int q = tid - 16384;
        int i = q >> 3, h = q & 7;
        float s = 0.f;
#pragma unroll
        for (int k = 0; k < 16; ++k)
            s += We[h*2048 + i*16 + k] * Wattn[h*48 + k];
        int col = 128 + h;
        int off = col*256 + (((i>>3) ^ (col&15))<<4) + (i&7)*2;
        *(unsigned short*)(Bcomb + off) = f2bf(s);
    } else if (tid < 33792) {
        int q = tid - 17408;
        int i = q >> 7, c = q & 127;
        int h = c >> 4, o = c & 15;
        Wn[i*128 + c] = Wh[h*2048 + i*16 + o];
    } else if (tid < 36864) {
        int q = tid - 33792;          // 24 cols * 128 k
        int col = 136 + (q >> 7), i = q & 127;
        int off = col*256 + (((i>>3) ^ (col&15))<<4) + (i&7)*2;
        *(unsigned short*)(Bcomb + off) = 0;
    }
}

// ---------------- f32 GEMM helpers (node GEMM only) ----------------
__device__ __forceinline__ void stage_ab(const float* __restrict__ Aglob,
                                         const float* __restrict__ Bglob,
                                         float* Al, float* Bl, int m0, int M)
{
    int t = threadIdx.x;
    {
        int r = t >> 2, kc = t & 3;
        int gr = m0 + r; if (gr >= M) gr = M - 1;
        const float4* s4 = (const float4*)(Aglob + (size_t)gr*128 + kc*32);
        float4* d4 = (float4*)(Al + r*APAD + kc*32);
#pragma unroll
        for (int i = 0; i < 8; ++i) d4[i] = s4[i];
    }
    {
        const float2* B2 = (const float2*)Bglob;
#pragma unroll
        for (int it = 0; it < 16; ++it) {
            int q = it*512 + t;
            int k = q >> 6, c2 = q & 63;
            int c = c2*2, g = c >> 3, j = c & 7;
            float2 v = B2[q];
            Bl[k*BSTR + g*10 + j]     = v.x;
            Bl[k*BSTR + g*10 + j + 1] = v.y;
        }
    }
}

__device__ __forceinline__ void mm_core(const float* Al, const float* Bl, float acc[4][8])
{
    int t = threadIdx.x;
    int rowg = t >> 4, colg = t & 15;
    int r0 = rowg * 4;
#pragma unroll
    for (int i = 0; i < 4; ++i)
#pragma unroll
        for (int j = 0; j < 8; ++j) acc[i][j] = 0.f;
#pragma unroll 4
    for (int k = 0; k < 128; ++k) {
        float a0 = Al[(r0+0)*APAD + k];
        float a1 = Al[(r0+1)*APAD + k];
        float a2 = Al[(r0+2)*APAD + k];
        float a3 = Al[(r0+3)*APAD + k];
        const float* bp = Bl + k*BSTR + colg*10;
#pragma unroll
        for (int j = 0; j < 8; ++j) {
            float b = bp[j];
            acc[0][j] += a0 * b;
            acc[1][j] += a1 * b;
            acc[2][j] += a2 * b;
            acc[3][j] += a3 * b;
        }
    }
}

// ---------------- node GEMM: z_h = h @ Wn (f32 + bf16 copy) ----------------
__global__ __launch_bounds__(512, 2) void k_node_gemm(const float* __restrict__ hg,
                                                      const float* __restrict__ Wn,
                                                      float* __restrict__ z_h,
                                                      unsigned short* __restrict__ z_hb)
{
    __shared__ float Al[128*APAD];
    __shared__ float Bl[128*BSTR];
    int m0 = blockIdx.x * 128;
    stage_ab(hg, Wn, Al, Bl, m0, NN);
    __syncthreads();
    float acc[4][8];
    mm_core(Al, Bl, acc);
    int t = threadIdx.x;
    int rowg = t >> 4, colg = t & 15, r0 = rowg*4;
#pragma unroll
    for (int i = 0; i < 4; ++i) {
        int gr = m0 + r0 + i;
        if (gr < NN) {
            float4* dp = (float4*)(z_h + (size_t)gr*128 + colg*8);
            dp[0] = make_float4(acc[i][0], acc[i][1], acc[i][2], acc[i][3]);
            dp[1] = make_float4(acc[i][4], acc[i][5], acc[i][6], acc[i][7]);
            u16x8 zb;
#pragma unroll
            for (int j = 0; j < 8; ++j) zb[j] = f2bf(acc[i][j]);
            *(u16x8*)(z_hb + (size_t)gr*128 + colg*8) = zb;
        }
    }
}

// ---------------- node post: p_sb/p_db (bf16) + a_s/a_d from z_h ----------------
__global__ __launch_bounds__(256) void k_nodepost(const float* __restrict__ z_h,
    const float* __restrict__ Wproj, const float* __restrict__ Wattn,
    unsigned short* __restrict__ p_sb, unsigned short* __restrict__ p_db,
    float* __restrict__ a_s, float* __restrict__ a_d)
{
    __shared__ float Wps[16*128], Wpd[16*128], Was[128], Wad[128];
    __shared__ float z2[2*140];
    int t = threadIdx.x;
    for (int q = t; q < 2048; q += 256) {
        int k = q >> 7, rest = q & 127, h = rest >> 4, o = rest & 15;
        Wps[q] = Wproj[h*768 + (16+k)*16 + o];
        Wpd[q] = Wproj[h*768 + (32+k)*16 + o];
    }
    if (t < 128) {
        int h = t >> 4, k = t & 15;
        Was[t] = Wattn[h*48 + 16 + k];
        Wad[t] = Wattn[h*48 + 32 + k];
    }
    int nh = t >> 7, rest = t & 127, hh = rest >> 4, oo = rest & 15;
    int n0 = blockIdx.x * 32;
    for (int it = 0; it < 16; ++it) {
        int n = n0 + it*2 + nh;
        __syncthreads();
        {
            float v = 0.f;
            if (n < NN) v = z_h[(size_t)n*128 + hh*16 + oo];
            z2[nh*140 + hh*17 + oo] = v;
        }
        __syncthreads();
        if (n < NN) {
            const float* zz = z2 + nh*140 + hh*17;
            float ps = 0.f, pd = 0.f, as_ = 0.f, ad_ = 0.f;
#pragma unroll
            for (int k = 0; k < 16; ++k) {
                float zv = zz[k];
                ps  += zv * Wps[k*128 + hh*16 + oo];
                pd  += zv * Wpd[k*128 + hh*16 + oo];
                as_ += zv * Was[hh*16 + k];
                ad_ += zv * Wad[hh*16 + k];
            }
            p_sb[(size_t)n*128 + rest] = f2bf(ps);
            p_db[(size_t)n*128 + rest] = f2bf(pd);
            if (oo == 0) { a_s[n*8 + hh] = as_; a_d[n*8 + hh] = ad_; }
        }
    }
}

// ---------------- edge GEMM (bf16 MFMA) + attn + e_out ----------------
// 256 threads = 4 waves, tile 128 rows x 160 cols, K=128 single shot.
// LDS: A bf16 swz 32KB + Bt bf16 swz 40KB, reused as C f32 [128][140] (cols 0..135).
union EdgeSM {
    struct { __align__(16) unsigned char A[32768]; __align__(16) unsigned char Bt[40960]; } s;
    float C[128*CSTR];
};

__global__ __launch_bounds__(256) void k_edge(const float* __restrict__ eg,
    const unsigned char* __restrict__ Bcomb, const float* __restrict__ bproj,
    const int* __restrict__ src, const int* __restrict__ dst,
    const unsigned short* __restrict__ p_sb, const unsigned short* __restrict__ p_db,
    const float* __restrict__ a_s, const float* __restrict__ a_d,
    float* __restrict__ attn, float* __restrict__ e_out)
{
    __shared__ EdgeSM sm;
    __shared__ float bpl[128];
    const int t = threadIdx.x;
    const int m0 = blockIdx.x * 128;

    // ---- stage A: f32 -> bf16, chunk-swizzled (chunk ^= row&15) ----
#pragma unroll
    for (int it = 0; it < 16; ++it) {
        int q = it*256 + t;                 // float4 id, 4096 total
        int row = q >> 5, c4 = q & 31;
        int gr = m0 + row; if (gr >= NE) gr = NE - 1;
        float4 v = *(const float4*)(eg + (size_t)gr*128 + c4*4);
        unsigned u0 = (unsigned)f2bf(v.x) | ((unsigned)f2bf(v.y) << 16);
        unsigned u1 = (unsigned)f2bf(v.z) | ((unsigned)f2bf(v.w) << 16);
        int off = row*256 + (((c4>>1) ^ (row&15))<<4) + (c4&1)*8;
        *(uint2*)(sm.s.A + off) = make_uint2(u0, u1);
    }
    // ---- stage Bt: bf16+swizzled in global, linear 40KB copy ----
    {
        const uint4* bsrc = (const uint4*)Bcomb;
        uint4* bdst = (uint4*)sm.s.Bt;
#pragma unroll
        for (int it = 0; it < 10; ++it) {
            int q = it*256 + t;
            bdst[q] = bsrc[q];
        }
    }
    if (t < 128) bpl[t] = bproj[t];
    __syncthreads();

    // ---- MFMA K-loop ----
    const int w = t >> 6, l = t & 63;
    const int lc = l & 15, lk = l >> 4;
    const int wm0 = (w >> 1) * 64, wn0 = (w & 1) * 80;
    f32x4 acc[4][5];
#pragma unroll
    for (int m = 0; m < 4; ++m)
#pragma unroll
        for (int n = 0; n < 5; ++n) acc[m][n] = (f32x4){0.f, 0.f, 0.f, 0.f};

#pragma unroll
    for (int ks = 0; ks < 4; ++ks) {
        const int swz = ((ks*4 + lk) ^ lc) << 4;
        bf16x8 af[4], bfr[5];
#pragma unroll
        for (int m = 0; m < 4; ++m) {
            int row = wm0 + m*16 + lc;
            af[m] = *(const bf16x8*)(sm.s.A + row*256 + swz);
        }
#pragma unroll
        for (int n = 0; n < 5; ++n) {
            int col = wn0 + n*16 + lc;
            bfr[n] = *(const bf16x8*)(sm.s.Bt + col*256 + swz);
        }
#pragma unroll
        for (int m = 0; m < 4; ++m)
#pragma unroll
            for (int n = 0; n < 5; ++n)
                acc[m][n] = __builtin_amdgcn_mfma_f32_16x16x32_bf16(af[m], bfr[n], acc[m][n], 0, 0, 0);
    }
    __syncthreads();   // all LDS frag reads done -> safe to overwrite as C

    // ---- bounce acc into LDS C[128][140] (cols 0..127 = e_proj, 128..135 = raw attn) ----
    {
#pragma unroll
        for (int m = 0; m < 4; ++m) {
            int rbase = wm0 + m*16 + lk*4;
#pragma unroll
            for (int n = 0; n < 5; ++n) {
                int col = wn0 + n*16 + lc;
                bool keep = (w & 1) ? (n < 3 || (n == 3 && lc < 8)) : true;
                if (keep) {
#pragma unroll
                    for (int i = 0; i < 4; ++i)
                        sm.C[(rbase + i)*CSTR + col] = acc[m][n][i];
                }
            }
        }
    }
    __syncthreads();

    // ---- attn pass: fully-coalesced float4 stores (1KB/wave-instr) ----
    {
        int row = t >> 1, g = t & 1;       // g: head group of 4
        int er = m0 + row;
        if (er < NE) {
            int sj = src[er], dj = dst[er];
            const float* Cp = &sm.C[row*CSTR + 128 + g*4];
            float4 as4 = *(const float4*)(a_s + (size_t)sj*8 + g*4);
            float4 ad4 = *(const float4*)(a_d + (size_t)dj*8 + g*4);
            float v0 = Cp[0] + as4.x + ad4.x;
            float v1 = Cp[1] + as4.y + ad4.y;
            float v2 = Cp[2] + as4.z + ad4.z;
            float v3 = Cp[3] + as4.w + ad4.w;
            v0 = v0 > 0.f ? v0 : 0.01f * v0;
            v1 = v1 > 0.f ? v1 : 0.01f * v1;
            v2 = v2 > 0.f ? v2 : 0.01f * v2;
            v3 = v3 > 0.f ? v3 : 0.01f * v3;
            *(float4*)(attn + (size_t)er*8 + g*4) = make_float4(v0, v1, v2, v3);
        }
    }

    // ---- e_out pass: 16 lanes own a row (full 512B rows per instr-pair) ----
    {
        int rowg = t >> 4, colg = t & 15;
#pragma unroll
        for (int i = 0; i < 8; ++i) {
            int r = rowg*8 + i;
            int er = m0 + r;
            if (er < NE) {
                int sj = src[er], dj = dst[er];
                u16x8 psv = *(const u16x8*)(p_sb + (size_t)sj*128 + colg*8);
                u16x8 pdv = *(const u16x8*)(p_db + (size_t)dj*128 + colg*8);
                const float4* evp = (const float4*)(eg + (size_t)er*128 + colg*8);
                float4 ev0 = evp[0], ev1 = evp[1];
                const float* Cp = &sm.C[r*CSTR + colg*8];
                float ov[8];
#pragma unroll
                for (int j = 0; j < 8; ++j) {
                    float val = Cp[j] + bf2f(psv[j]) + bf2f(pdv[j]) + bpl[colg*8 + j];
                    ov[j] = val > 0.f ? val : expm1f(val);
                }
                float4* op = (float4*)(e_out + (size_t)er*128 + colg*8);
                op[0] = make_float4(ev0.x + ov[0], ev0.y + ov[1], ev0.z + ov[2], ev0.w + ov[3]);
                op[1] = make_float4(ev1.x + ov[4], ev1.y + ov[5], ev1.z + ov[6], ev1.w + ov[7]);
            }
        }
    }
}

// ---------------- CSR build ----------------
__global__ void k_hist(const int* __restrict__ dst, int* __restrict__ deg)
{
    int e = blockIdx.x*256 + threadIdx.x;
    if (e < NE) atomicAdd(&deg[dst[e]], 1);
}

__global__ __launch_bounds__(1024) void k_scan1(const int* __restrict__ deg,
                                                int* __restrict__ offs, int* __restrict__ bsum)
{
    __shared__ int s[1024];
    int t = threadIdx.x;
    int idx = blockIdx.x*1024 + t;
    int v = (idx < NN) ? deg[idx] : 0;
    s[t] = v;
    __syncthreads();
    for (int off = 1; off < 1024; off <<= 1) {
        int x = (t >= off) ? s[t - off] : 0;
        __syncthreads();
        s[t] += x;
        __syncthreads();
    }
    if (idx < NN) offs[idx] = s[t] - v;
    if (t == 1023) bsum[blockIdx.x] = s[1023];
}

__global__ void k_scan2(const int* __restrict__ bsum, int* __restrict__ bases)
{
    int i = threadIdx.x;
    int v = (i < 49) ? bsum[i] : 0;
    int incl = v;
#pragma unroll
    for (int off = 1; off < 64; off <<= 1) {
        int x = __shfl_up(incl, off, 64);
        if (i >= off) incl += x;
    }
    if (i < 49) bases[i] = incl - v;
}

__global__ void k_scan3(int* __restrict__ offs, const int* __restrict__ bases,
                        int* __restrict__ cursor)
{
    int n = blockIdx.x*256 + threadIdx.x;
    if (n < NN) {
        int v = offs[n] + bases[n >> 10];
        offs[n] = v;
        cursor[n] = v;
    }
}

__global__ void k_scatter(const int* __restrict__ dst, int* __restrict__ cursor,
                          int* __restrict__ eids)
{
    int e = blockIdx.x*256 + threadIdx.x;
    if (e < NE) {
        int p = atomicAdd(&cursor[dst[e]], 1);
        eids[p] = e;
    }
}

// ---------------- per-node segment softmax + aggregate (bf16 z gather) ----------------
__global__ __launch_bounds__(256) void k_agg(const float* __restrict__ hg,
    const unsigned short* __restrict__ z_hb, const float* __restrict__ attn,
    const int* __restrict__ eids, const int* __restrict__ offs, const int* __restrict__ deg,
    const int* __restrict__ src, float* __restrict__ h_out)
{
    int half = threadIdx.x >> 7;
    int t = threadIdx.x & 127;
    int n = blockIdx.x * 2 + half;
    int hh = t >> 4;
    int dg = deg[n];
    int o0 = offs[n];
    float m = -INFINITY;
    for (int j = (t & 15); j < dg; j += 16) {
        int e = eids[o0 + j];
        m = fmaxf(m, attn[(size_t)e*8 + hh]);
    }
#pragma unroll
    for (int s = 1; s < 16; s <<= 1) m = fmaxf(m, __shfl_xor(m, s, 64));

    float n0 = 0.f, n1 = 0.f, n2 = 0.f, n3 = 0.f;
    float d0 = 0.f, d1 = 0.f, d2 = 0.f, d3 = 0.f;
    int j = 0;
    for (; j + 4 <= dg; j += 4) {
        int e0 = eids[o0 + j + 0];
        int e1 = eids[o0 + j + 1];
        int e2 = eids[o0 + j + 2];
        int e3 = eids[o0 + j + 3];
        int s0 = src[e0], s1 = src[e1], s2 = src[e2], s3 = src[e3];
        float x0 = expf(attn[(size_t)e0*8 + hh] - m);
        float x1 = expf(attn[(size_t)e1*8 + hh] - m);
        float x2 = expf(attn[(size_t)e2*8 + hh] - m);
        float x3 = expf(attn[(size_t)e3*8 + hh] - m);
        d0 += x0; d1 += x1; d2 += x2; d3 += x3;
        n0 += x0 * bf2f(z_hb[(size_t)s0*128 + t]);
        n1 += x1 * bf2f(z_hb[(size_t)s1*128 + t]);
        n2 += x2 * bf2f(z_hb[(size_t)s2*128 + t]);
        n3 += x3 * bf2f(z_hb[(size_t)s3*128 + t]);
    }
    for (; j < dg; ++j) {
        int e = eids[o0 + j];
        float x = expf(attn[(size_t)e*8 + hh] - m);
        d0 += x;
        n0 += x * bf2f(z_hb[(size_t)src[e]*128 + t]);
    }
    float num = (n0 + n1) + (n2 + n3);
    float den = (d0 + d1) + (d2 + d3);
    float hag = num / fmaxf(den, 1e-9f);
    float el = hag > 0.f ? hag : expm1f(hag);
    h_out[(size_t)n*128 + t] = hg[(size_t)n*128 + t] + el;
}

// ---------------- launcher ----------------
extern "C" void kernel_launch(void* const* d_in, const int* in_sizes, int n_in,
                              void* d_out, int out_size, void* d_ws, size_t ws_size,
                              hipStream_t stream)
{
    const float* h     = (const float*)d_in[0];
    const float* e     = (const float*)d_in[1];
    const int*   src   = (const int*)d_in[2];
    const int*   dst   = (const int*)d_in[3];
    const float* Wh    = (const float*)d_in[4];
    const float* We    = (const float*)d_in[5];
    const float* Wproj = (const float*)d_in[6];
    const float* bproj = (const float*)d_in[7];
    const float* Wattn = (const float*)d_in[8];
    float* h_out = (float*)d_out;
    float* e_out = h_out + (size_t)NN * 128;

    char* w = (char*)d_ws;
    auto alloc = [&](size_t bytes) {
        char* p = w;
        w += (bytes + 255) & ~(size_t)255;
        return p;
    };
    unsigned char* Bcomb = (unsigned char*)alloc(160 * 256);            // bf16 swizzled B
    float* Wn   = (float*)alloc(16384 * 4);
    float* z_h  = (float*)alloc((size_t)NN * 128 * 4);
    unsigned short* z_hb = (unsigned short*)alloc((size_t)NN * 128 * 2);
    unsigned short* p_sb = (unsigned short*)alloc((size_t)NN * 128 * 2);
    unsigned short* p_db = (unsigned short*)alloc((size_t)NN * 128 * 2);
    float* a_s  = (float*)alloc((size_t)NN * 8 * 4);
    float* a_d  = (float*)alloc((size_t)NN * 8 * 4);
    float* attn = (float*)alloc((size_t)NE * 8 * 4);
    int* deg    = (int*)alloc((size_t)NN * 4);
    int* offs   = (int*)alloc((size_t)NN * 4);
    int* cursor = (int*)alloc((size_t)NN * 4);
    int* eids   = (int*)alloc((size_t)NE * 4);
    int* bsum   = (int*)alloc(64 * 4);
    int* bases  = (int*)alloc(64 * 4);

    hipMemsetAsync(deg, 0, (size_t)NN * 4, stream);

    k_combine<<<144, 256, 0, stream>>>(Wh, We, Wproj, Wattn, Bcomb, Wn);
    k_node_gemm<<<(NN + 127) / 128, 512, 0, stream>>>(h, Wn, z_h, z_hb);
    k_nodepost<<<(NN + 31) / 32, 256, 0, stream>>>(z_h, Wproj, Wattn, p_sb, p_db, a_s, a_d);
    k_edge<<<(NE + 127) / 128, 256, 0, stream>>>(e, Bcomb, bproj, src, dst,
                                                 p_sb, p_db, a_s, a_d, attn, e_out);
    k_hist<<<(NE + 255) / 256, 256, 0, stream>>>(dst, deg);
    k_scan1<<<49, 1024, 0, stream>>>(deg, offs, bsum);
    k_scan2<<<1, 64, 0, stream>>>(bsum, bases);
    k_scan3<<<(NN + 255) / 256, 256, 0, stream>>>(offs, bases, cursor);
    k_scatter<<<(NE + 255) / 256, 256, 0, stream>>>(dst, cursor, eids);
    k_agg<<<NN / 2, 256, 0, stream>>>(h, z_hb, attn, eids, offs, deg, src, h_out);
}

// Round 7
// 861.741 us; speedup vs baseline: 1.7773x; 1.0542x over previous
//
#include <hip/hip_runtime.h>
#include <math.h>

// GAT layer w/ edge features.
// Edge+node GEMMs in bf16 MFMA. CSR segment softmax, single-pass exp (no max
// subtraction -- ratio identical, attn bounded ~11), permuted attn/src arrays
// remove eids indirection from k_agg. Register-blocked nodepost.

constexpr int NN = 50000;
constexpr int NE = 600000;
constexpr int CSTR = 140;   // k_edge LDS C stride (cols 0..135 used)
constexpr int CST2 = 132;   // k_node LDS C stride

typedef __attribute__((ext_vector_type(8))) short bf16x8;
typedef __attribute__((ext_vector_type(8))) unsigned short u16x8;
typedef __attribute__((ext_vector_type(4))) float f32x4;

__device__ __forceinline__ unsigned short f2bf(float f) {
    unsigned u = __float_as_uint(f);
    u += 0x7fffu + ((u >> 16) & 1u);   // RNE
    return (unsigned short)(u >> 16);
}
__device__ __forceinline__ float bf2f(unsigned short us) {
    return __uint_as_float((unsigned)us << 16);
}

// ---------------- weight combine ----------------
// Bcomb (bf16, swizzled, [160 cols][128 k], 256B/col): edge GEMM B
//   cols 0..127 : WecT[c][i] = sum_k We[h][i][k]*Wproj[h][k][o]  (c=h*16+o)
//   cols 128..135: Ae[i][h], cols 136..159: 0
// Bn (bf16, swizzled, [128 cols][128 k]): node GEMM B, Bn[i][c] = Wh[h][i][o]
// byte offset for (col, k-dim i): col*256 + ((i>>3)^(col&15))*16 + (i&7)*2
__global__ void k_combine(const float* __restrict__ Wh, const float* __restrict__ We,
                          const float* __restrict__ Wproj, const float* __restrict__ Wattn,
                          unsigned char* __restrict__ Bcomb, unsigned char* __restrict__ Bn)
{
    int tid = blockIdx.x * 256 + threadIdx.x;
    if (tid < 16384) {
        int i = tid >> 7, c = tid & 127;
        int h = c >> 4, o = c & 15;
        float s = 0.f;
#pragma unroll
        for (int k = 0; k < 16; ++k)
            s += We[h*2048 + i*16 + k] * Wproj[h*768 + k*16 + o];
        int off = c*256 + (((i>>3) ^ (c&15))<<4) + (i&7)*2;
        *(unsigned short*)(Bcomb + off) = f2bf(s);
    } else if (tid < 17408) {
        int q = tid - 16384;
        int i = q >> 3, h = q & 7;
        float s = 0.f;
#pragma unroll
        for (int k = 0; k < 16; ++k)
            s += We[h*2048 + i*16 + k] * Wattn[h*48 + k];
        int col = 128 + h;
        int off = col*256 + (((i>>3) ^ (col&15))<<4) + (i&7)*2;
        *(unsigned short*)(Bcomb + off) = f2bf(s);
    } else if (tid < 33792) {
        int q = tid - 17408;
        int i = q >> 7, c = q & 127;
        int h = c >> 4, o = c & 15;
        int off = c*256 + (((i>>3) ^ (c&15))<<4) + (i&7)*2;
        *(unsigned short*)(Bn + off) = f2bf(Wh[h*2048 + i*16 + o]);
    } else if (tid < 36864) {
        int q = tid - 33792;          // 24 zero cols of Bcomb
        int col = 136 + (q >> 7), i = q & 127;
        int off = col*256 + (((i>>3) ^ (col&15))<<4) + (i&7)*2;
        *(unsigned short*)(Bcomb + off) = 0;
    }
}

// ---------------- node GEMM (bf16 MFMA): z_h = h @ Wn ----------------
// 256 threads = 4 waves, tile 128x128, K=128. Wave grid 2x2, wave tile 64x64.
union NodeSM {
    struct { __align__(16) unsigned char A[32768]; __align__(16) unsigned char Bt[32768]; } s;
    float C[128*CST2];
};

__global__ __launch_bounds__(256) void k_node_gemm(const float* __restrict__ hg,
    const unsigned char* __restrict__ Bn,
    float* __restrict__ z_h, unsigned short* __restrict__ z_hb)
{
    __shared__ NodeSM sm;
    const int t = threadIdx.x;
    const int m0 = blockIdx.x * 128;

    // stage A: f32 -> bf16, chunk-swizzled
#pragma unroll
    for (int it = 0; it < 16; ++it) {
        int q = it*256 + t;
        int row = q >> 5, c4 = q & 31;
        int gr = m0 + row; if (gr >= NN) gr = NN - 1;
        float4 v = *(const float4*)(hg + (size_t)gr*128 + c4*4);
        unsigned u0 = (unsigned)f2bf(v.x) | ((unsigned)f2bf(v.y) << 16);
        unsigned u1 = (unsigned)f2bf(v.z) | ((unsigned)f2bf(v.w) << 16);
        int off = row*256 + (((c4>>1) ^ (row&15))<<4) + (c4&1)*8;
        *(uint2*)(sm.s.A + off) = make_uint2(u0, u1);
    }
    // stage Bt: linear 32KB copy
    {
        const uint4* bsrc = (const uint4*)Bn;
        uint4* bdst = (uint4*)sm.s.Bt;
#pragma unroll
        for (int it = 0; it < 8; ++it) bdst[it*256 + t] = bsrc[it*256 + t];
    }
    __syncthreads();

    const int w = t >> 6, l = t & 63;
    const int lc = l & 15, lk = l >> 4;
    const int wm0 = (w >> 1) * 64, wn0 = (w & 1) * 64;
    f32x4 acc[4][4];
#pragma unroll
    for (int m = 0; m < 4; ++m)
#pragma unroll
        for (int n = 0; n < 4; ++n) acc[m][n] = (f32x4){0.f, 0.f, 0.f, 0.f};

#pragma unroll
    for (int ks = 0; ks < 4; ++ks) {
        const int swz = ((ks*4 + lk) ^ lc) << 4;
        bf16x8 af[4], bfr[4];
#pragma unroll
        for (int m = 0; m < 4; ++m)
            af[m] = *(const bf16x8*)(sm.s.A + (wm0 + m*16 + lc)*256 + swz);
#pragma unroll
        for (int n = 0; n < 4; ++n)
            bfr[n] = *(const bf16x8*)(sm.s.Bt + (wn0 + n*16 + lc)*256 + swz);
#pragma unroll
        for (int m = 0; m < 4; ++m)
#pragma unroll
            for (int n = 0; n < 4; ++n)
                acc[m][n] = __builtin_amdgcn_mfma_f32_16x16x32_bf16(af[m], bfr[n], acc[m][n], 0, 0, 0);
    }
    __syncthreads();

    // bounce into LDS C
#pragma unroll
    for (int m = 0; m < 4; ++m) {
        int rbase = wm0 + m*16 + lk*4;
#pragma unroll
        for (int n = 0; n < 4; ++n) {
            int col = wn0 + n*16 + lc;
#pragma unroll
            for (int i = 0; i < 4; ++i)
                sm.C[(rbase + i)*CST2 + col] = acc[m][n][i];
        }
    }
    __syncthreads();

    // full-row writes: z_h f32 + z_hb bf16
    {
        int rowg = t >> 4, colg = t & 15;
#pragma unroll
        for (int i = 0; i < 8; ++i) {
            int r = rowg*8 + i;
            int gr = m0 + r;
            if (gr < NN) {
                const float* Cp = &sm.C[r*CST2 + colg*8];
                float4 c0 = *(const float4*)&Cp[0];
                float4 c1 = *(const float4*)&Cp[4];
                float4* dp = (float4*)(z_h + (size_t)gr*128 + colg*8);
                dp[0] = c0; dp[1] = c1;
                u16x8 zb;
                zb[0] = f2bf(c0.x); zb[1] = f2bf(c0.y); zb[2] = f2bf(c0.z); zb[3] = f2bf(c0.w);
                zb[4] = f2bf(c1.x); zb[5] = f2bf(c1.y); zb[6] = f2bf(c1.z); zb[7] = f2bf(c1.w);
                *(u16x8*)(z_hb + (size_t)gr*128 + colg*8) = zb;
            }
        }
    }
}

// ---------------- node post: register-blocked weights ----------------
// Thread owns (h,o); 64 weights in VGPRs; z via 16 broadcast LDS reads/node.
__global__ __launch_bounds__(256) void k_nodepost(const float* __restrict__ z_h,
    const float* __restrict__ Wproj, const float* __restrict__ Wattn,
    unsigned short* __restrict__ p_sb, unsigned short* __restrict__ p_db,
    float* __restrict__ a_s, float* __restrict__ a_d)
{
    __shared__ float z2[2][136];   // head-stride 17
    int t = threadIdx.x;
    int nh = t >> 7, rest = t & 127, hh = rest >> 4, oo = rest & 15;

    float wps[16], wpd[16], was_r[16], wad_r[16];
#pragma unroll
    for (int k = 0; k < 16; ++k) {
        wps[k]   = Wproj[hh*768 + (16+k)*16 + oo];
        wpd[k]   = Wproj[hh*768 + (32+k)*16 + oo];
        was_r[k] = Wattn[hh*48 + 16 + k];
        wad_r[k] = Wattn[hh*48 + 32 + k];
    }

    int n0 = blockIdx.x * 32;
    for (int it = 0; it < 16; ++it) {
        int n = n0 + it*2 + nh;
        __syncthreads();
        z2[nh][hh*17 + oo] = (n < NN) ? z_h[(size_t)n*128 + rest] : 0.f;
        __syncthreads();
        if (n < NN) {
            const float* zz = &z2[nh][hh*17];
            float ps = 0.f, pd = 0.f, as_ = 0.f, ad_ = 0.f;
#pragma unroll
            for (int k = 0; k < 16; ++k) {
                float zv = zz[k];
                ps  += zv * wps[k];
                pd  += zv * wpd[k];
                as_ += zv * was_r[k];
                ad_ += zv * wad_r[k];
            }
            p_sb[(size_t)n*128 + rest] = f2bf(ps);
            p_db[(size_t)n*128 + rest] = f2bf(pd);
            if (oo == 0) { a_s[n*8 + hh] = as_; a_d[n*8 + hh] = ad_; }
        }
    }
}

// ---------------- edge GEMM (bf16 MFMA) + attn + e_out ----------------
union EdgeSM {
    struct { __align__(16) unsigned char A[32768]; __align__(16) unsigned char Bt[40960]; } s;
    float C[128*CSTR];
};

__global__ __launch_bounds__(256) void k_edge(const float* __restrict__ eg,
    const unsigned char* __restrict__ Bcomb, const float* __restrict__ bproj,
    const int* __restrict__ src, const int* __restrict__ dst,
    const unsigned short* __restrict__ p_sb, const unsigned short* __restrict__ p_db,
    const float* __restrict__ a_s, const float* __restrict__ a_d,
    float* __restrict__ attn, float* __restrict__ e_out)
{
    __shared__ EdgeSM sm;
    __shared__ float bpl[128];
    const int t = threadIdx.x;
    const int m0 = blockIdx.x * 128;

#pragma unroll
    for (int it = 0; it < 16; ++it) {
        int q = it*256 + t;
        int row = q >> 5, c4 = q & 31;
        int gr = m0 + row; if (gr >= NE) gr = NE - 1;
        float4 v = *(const float4*)(eg + (size_t)gr*128 + c4*4);
        unsigned u0 = (unsigned)f2bf(v.x) | ((unsigned)f2bf(v.y) << 16);
        unsigned u1 = (unsigned)f2bf(v.z) | ((unsigned)f2bf(v.w) << 16);
        int off = row*256 + (((c4>>1) ^ (row&15))<<4) + (c4&1)*8;
        *(uint2*)(sm.s.A + off) = make_uint2(u0, u1);
    }
    {
        const uint4* bsrc = (const uint4*)Bcomb;
        uint4* bdst = (uint4*)sm.s.Bt;
#pragma unroll
        for (int it = 0; it < 10; ++it) bdst[it*256 + t] = bsrc[it*256 + t];
    }
    if (t < 128) bpl[t] = bproj[t];
    __syncthreads();

    const int w = t >> 6, l = t & 63;
    const int lc = l & 15, lk = l >> 4;
    const int wm0 = (w >> 1) * 64, wn0 = (w & 1) * 80;
    f32x4 acc[4][5];
#pragma unroll
    for (int m = 0; m < 4; ++m)
#pragma unroll
        for (int n = 0; n < 5; ++n) acc[m][n] = (f32x4){0.f, 0.f, 0.f, 0.f};

#pragma unroll
    for (int ks = 0; ks < 4; ++ks) {
        const int swz = ((ks*4 + lk) ^ lc) << 4;
        bf16x8 af[4], bfr[5];
#pragma unroll
        for (int m = 0; m < 4; ++m)
            af[m] = *(const bf16x8*)(sm.s.A + (wm0 + m*16 + lc)*256 + swz);
#pragma unroll
        for (int n = 0; n < 5; ++n)
            bfr[n] = *(const bf16x8*)(sm.s.Bt + (wn0 + n*16 + lc)*256 + swz);
#pragma unroll
        for (int m = 0; m < 4; ++m)
#pragma unroll
            for (int n = 0; n < 5; ++n)
                acc[m][n] = __builtin_amdgcn_mfma_f32_16x16x32_bf16(af[m], bfr[n], acc[m][n], 0, 0, 0);
    }
    __syncthreads();

    {
#pragma unroll
        for (int m = 0; m < 4; ++m) {
            int rbase = wm0 + m*16 + lk*4;
#pragma unroll
            for (int n = 0; n < 5; ++n) {
                int col = wn0 + n*16 + lc;
                bool keep = (w & 1) ? (n < 3 || (n == 3 && lc < 8)) : true;
                if (keep) {
#pragma unroll
                    for (int i = 0; i < 4; ++i)
                        sm.C[(rbase + i)*CSTR + col] = acc[m][n][i];
                }
            }
        }
    }
    __syncthreads();

    // attn pass
    {
        int row = t >> 1, g = t & 1;
        int er = m0 + row;
        if (er < NE) {
            int sj = src[er], dj = dst[er];
            const float* Cp = &sm.C[row*CSTR + 128 + g*4];
            float4 as4 = *(const float4*)(a_s + (size_t)sj*8 + g*4);
            float4 ad4 = *(const float4*)(a_d + (size_t)dj*8 + g*4);
            float v0 = Cp[0] + as4.x + ad4.x;
            float v1 = Cp[1] + as4.y + ad4.y;
            float v2 = Cp[2] + as4.z + ad4.z;
            float v3 = Cp[3] + as4.w + ad4.w;
            v0 = v0 > 0.f ? v0 : 0.01f * v0;
            v1 = v1 > 0.f ? v1 : 0.01f * v1;
            v2 = v2 > 0.f ? v2 : 0.01f * v2;
            v3 = v3 > 0.f ? v3 : 0.01f * v3;
            *(float4*)(attn + (size_t)er*8 + g*4) = make_float4(v0, v1, v2, v3);
        }
    }

    // e_out pass
    {
        int rowg = t >> 4, colg = t & 15;
#pragma unroll
        for (int i = 0; i < 8; ++i) {
            int r = rowg*8 + i;
            int er = m0 + r;
            if (er < NE) {
                int sj = src[er], dj = dst[er];
                u16x8 psv = *(const u16x8*)(p_sb + (size_t)sj*128 + colg*8);
                u16x8 pdv = *(const u16x8*)(p_db + (size_t)dj*128 + colg*8);
                const float4* evp = (const float4*)(eg + (size_t)er*128 + colg*8);
                float4 ev0 = evp[0], ev1 = evp[1];
                const float* Cp = &sm.C[r*CSTR + colg*8];
                float ov[8];
#pragma unroll
                for (int j = 0; j < 8; ++j) {
                    float val = Cp[j] + bf2f(psv[j]) + bf2f(pdv[j]) + bpl[colg*8 + j];
                    ov[j] = val > 0.f ? val : expm1f(val);
                }
                float4* op = (float4*)(e_out + (size_t)er*128 + colg*8);
                op[0] = make_float4(ev0.x + ov[0], ev0.y + ov[1], ev0.z + ov[2], ev0.w + ov[3]);
                op[1] = make_float4(ev1.x + ov[4], ev1.y + ov[5], ev1.z + ov[6], ev1.w + ov[7]);
            }
        }
    }
}

// ---------------- CSR build ----------------
__global__ void k_hist(const int* __restrict__ dst, int* __restrict__ deg)
{
    int e = blockIdx.x*256 + threadIdx.x;
    if (e < NE) atomicAdd(&deg[dst[e]], 1);
}

__global__ __launch_bounds__(1024) void k_scan1(const int* __restrict__ deg,
                                                int* __restrict__ offs, int* __restrict__ bsum)
{
    __shared__ int s[1024];
    int t = threadIdx.x;
    int idx = blockIdx.x*1024 + t;
    int v = (idx < NN) ? deg[idx] : 0;
    s[t] = v;
    __syncthreads();
    for (int off = 1; off < 1024; off <<= 1) {
        int x = (t >= off) ? s[t - off] : 0;
        __syncthreads();
        s[t] += x;
        __syncthreads();
    }
    if (idx < NN) offs[idx] = s[t] - v;
    if (t == 1023) bsum[blockIdx.x] = s[1023];
}

__global__ void k_scan2(const int* __restrict__ bsum, int* __restrict__ bases)
{
    int i = threadIdx.x;
    int v = (i < 49) ? bsum[i] : 0;
    int incl = v;
#pragma unroll
    for (int off = 1; off < 64; off <<= 1) {
        int x = __shfl_up(incl, off, 64);
        if (i >= off) incl += x;
    }
    if (i < 49) bases[i] = incl - v;
}

__global__ void k_scan3(int* __restrict__ offs, const int* __restrict__ bases,
                        int* __restrict__ cursor)
{
    int n = blockIdx.x*256 + threadIdx.x;
    if (n < NN) {
        int v = offs[n] + bases[n >> 10];
        offs[n] = v;
        cursor[n] = v;
    }
}

__global__ void k_scatter(const int* __restrict__ dst, int* __restrict__ cursor,
                          int* __restrict__ eids)
{
    int e = blockIdx.x*256 + threadIdx.x;
    if (e < NE) {
        int p = atomicAdd(&cursor[dst[e]], 1);
        eids[p] = e;
    }
}

// ---------------- permute attn/src into CSR order ----------------
__global__ void k_permute(const int* __restrict__ eids, const int* __restrict__ src,
                          const float* __restrict__ attn,
                          int* __restrict__ src_perm, float* __restrict__ attn_perm)
{
    int p = blockIdx.x*256 + threadIdx.x;
    if (p < NE) {
        int e = eids[p];
        src_perm[p] = src[e];
        const float4* ap = (const float4*)(attn + (size_t)e*8);
        float4 a0 = ap[0], a1 = ap[1];
        float4* op = (float4*)(attn_perm + (size_t)p*8);
        op[0] = a0; op[1] = a1;
    }
}

// ---------------- per-node aggregate: single pass, no max ----------------
// exp(attn) without max-subtraction: ratio identical; attn bounded ~11.
__global__ __launch_bounds__(256) void k_agg(const float* __restrict__ hg,
    const unsigned short* __restrict__ z_hb, const float* __restrict__ attn_perm,
    const int* __restrict__ src_perm, const int* __restrict__ offs,
    const int* __restrict__ deg, float* __restrict__ h_out)
{
    int half = threadIdx.x >> 7;
    int t = threadIdx.x & 127;
    int n = blockIdx.x * 2 + half;
    int hh = t >> 4;
    int dg = deg[n];
    int o0 = offs[n];

    float n0 = 0.f, n1 = 0.f, n2 = 0.f, n3 = 0.f;
    float d0 = 0.f, d1 = 0.f, d2 = 0.f, d3 = 0.f;
    int j = 0;
    for (; j + 4 <= dg; j += 4) {
        int s0 = src_perm[o0 + j + 0];
        int s1 = src_perm[o0 + j + 1];
        int s2 = src_perm[o0 + j + 2];
        int s3 = src_perm[o0 + j + 3];
        float x0 = expf(attn_perm[(size_t)(o0 + j + 0)*8 + hh]);
        float x1 = expf(attn_perm[(size_t)(o0 + j + 1)*8 + hh]);
        float x2 = expf(attn_perm[(size_t)(o0 + j + 2)*8 + hh]);
        float x3 = expf(attn_perm[(size_t)(o0 + j + 3)*8 + hh]);
        d0 += x0; d1 += x1; d2 += x2; d3 += x3;
        n0 += x0 * bf2f(z_hb[(size_t)s0*128 + t]);
        n1 += x1 * bf2f(z_hb[(size_t)s1*128 + t]);
        n2 += x2 * bf2f(z_hb[(size_t)s2*128 + t]);
        n3 += x3 * bf2f(z_hb[(size_t)s3*128 + t]);
    }
    for (; j < dg; ++j) {
        int s = src_perm[o0 + j];
        float x = expf(attn_perm[(size_t)(o0 + j)*8 + hh]);
        d0 += x;
        n0 += x * bf2f(z_hb[(size_t)s*128 + t]);
    }
    float num = (n0 + n1) + (n2 + n3);
    float den = (d0 + d1) + (d2 + d3);
    float hag = num / fmaxf(den, 1e-9f);
    float el = hag > 0.f ? hag : expm1f(hag);
    h_out[(size_t)n*128 + t] = hg[(size_t)n*128 + t] + el;
}

// ---------------- launcher ----------------
extern "C" void kernel_launch(void* const* d_in, const int* in_sizes, int n_in,
                              void* d_out, int out_size, void* d_ws, size_t ws_size,
                              hipStream_t stream)
{
    const float* h     = (const float*)d_in[0];
    const float* e     = (const float*)d_in[1];
    const int*   src   = (const int*)d_in[2];
    const int*   dst   = (const int*)d_in[3];
    const float* Wh    = (const float*)d_in[4];
    const float* We    = (const float*)d_in[5];
    const float* Wproj = (const float*)d_in[6];
    const float* bproj = (const float*)d_in[7];
    const float* Wattn = (const float*)d_in[8];
    float* h_out = (float*)d_out;
    float* e_out = h_out + (size_t)NN * 128;

    char* w = (char*)d_ws;
    auto alloc = [&](size_t bytes) {
        char* p = w;
        w += (bytes + 255) & ~(size_t)255;
        return p;
    };
    unsigned char* Bcomb = (unsigned char*)alloc(160 * 256);
    unsigned char* Bn    = (unsigned char*)alloc(128 * 256);
    float* z_h  = (float*)alloc((size_t)NN * 128 * 4);
    unsigned short* z_hb = (unsigned short*)alloc((size_t)NN * 128 * 2);
    unsigned short* p_sb = (unsigned short*)alloc((size_t)NN * 128 * 2);
    unsigned short* p_db = (unsigned short*)alloc((size_t)NN * 128 * 2);
    float* a_s  = (float*)alloc((size_t)NN * 8 * 4);
    float* a_d  = (float*)alloc((size_t)NN * 8 * 4);
    float* attn = (float*)alloc((size_t)NE * 8 * 4);
    int* deg    = (int*)alloc((size_t)NN * 4);
    int* offs   = (int*)alloc((size_t)NN * 4);
    int* cursor = (int*)alloc((size_t)NN * 4);
    int* eids   = (int*)alloc((size_t)NE * 4);
    int* bsum   = (int*)alloc(64 * 4);
    int* bases  = (int*)alloc(64 * 4);
    // dead-after-k_edge overlays (p_sb+p_db contiguous 25.6MB >= 19.2MB;
    // a_s+a_d contiguous 3.2MB >= 2.4MB):
    float* attn_perm = (float*)p_sb;
    int*   src_perm  = (int*)a_s;

    hipMemsetAsync(deg, 0, (size_t)NN * 4, stream);

    k_combine<<<144, 256, 0, stream>>>(Wh, We, Wproj, Wattn, Bcomb, Bn);
    k_node_gemm<<<(NN + 127) / 128, 256, 0, stream>>>(h, Bn, z_h, z_hb);
    k_nodepost<<<(NN + 31) / 32, 256, 0, stream>>>(z_h, Wproj, Wattn, p_sb, p_db, a_s, a_d);
    k_edge<<<(NE + 127) / 128, 256, 0, stream>>>(e, Bcomb, bproj, src, dst,
                                                 p_sb, p_db, a_s, a_d, attn, e_out);
    k_hist<<<(NE + 255) / 256, 256, 0, stream>>>(dst, deg);
    k_scan1<<<49, 1024, 0, stream>>>(deg, offs, bsum);
    k_scan2<<<1, 64, 0, stream>>>(bsum, bases);
    k_scan3<<<(NN + 255) / 256, 256, 0, stream>>>(offs, bases, cursor);
    k_scatter<<<(NE + 255) / 256, 256, 0, stream>>>(dst, cursor, eids);
    k_permute<<<(NE + 255) / 256, 256, 0, stream>>>(eids, src, attn, src_perm, attn_perm);
    k_agg<<<NN / 2, 256, 0, stream>>>(h, z_hb, attn_perm, src_perm, offs, deg, h_out);
}